// Round 7
// baseline (147.332 us; speedup 1.0000x reference)
//
#include <hip/hip_runtime.h>
#include <math.h>

#define NPTS 4096
#define KNN  20
#define NOUT 64
#define QPB  8               // queries (= waves) per block
#define BLKT (QPB * 64)      // 512 threads
#define PCAP 128             // per-wave survivor pool capacity
#define HALF 2048            // candidates staged in LDS (phase A)

// monotone float->uint map (total order preserved)
__device__ __forceinline__ unsigned ord32(float f) {
    unsigned u = __float_as_uint(f);
    int m = ((int)u) >> 31;
    return u ^ ((unsigned)m | 0x80000000u);
}

__device__ __forceinline__ int mbcnt64(unsigned long long m) {
    return __builtin_amdgcn_mbcnt_hi((unsigned)(m >> 32),
           __builtin_amdgcn_mbcnt_lo((unsigned)m, 0));
}

// prologue: xq[b][j] = (x0, x1, x2, -(x0^2+x1^2+x2^2))
__global__ __launch_bounds__(256) void pack_kernel(const float* __restrict__ x,
                                                   float4* __restrict__ xq) {
    const int i = blockIdx.x * 256 + threadIdx.x;   // over B*NPTS
    const int b = i >> 12, j = i & (NPTS - 1);
    const float* xb = x + (size_t)b * 3 * NPTS;
    const float a0 = xb[j], a1 = xb[NPTS + j], a2 = xb[2 * NPTS + j];
    xq[i] = make_float4(a0, a1, a2, -fmaf(a0, a0, fmaf(a1, a1, a2 * a2)));
}

__global__ __launch_bounds__(BLKT, 6) void edgeconv_kernel(
    const float4* __restrict__ xq,    // (B, N) packed points
    const float* __restrict__ Wm,     // (64, 6)
    const float* __restrict__ gamma,
    const float* __restrict__ beta,
    const float* __restrict__ mean,
    const float* __restrict__ var,
    float* __restrict__ out)          // (B, 64, N)
{
    const int bid = blockIdx.x;
    const int b   = bid >> 9;                    // 512 blocks per batch
    const int n0  = (bid & 511) * QPB;
    const int t    = threadIdx.x;
    const int lane = t & 63;
    const int w    = t >> 6;

    __shared__ float4 tile[HALF];                       // 32 KB, candidates 0..2047
    __shared__ unsigned long long pool[QPB * PCAP];     // 8 KB; reused as outT later
    __shared__ unsigned idxs[QPB][KNN];                 // dedicated winner buffer

    const float4* xqb = xq + (size_t)b * NPTS;

    // ---- stage phase-A points into LDS ----
    #pragma unroll
    for (int k2 = 0; k2 < HALF / BLKT; ++k2) {          // 4 iters
        const int c = t + k2 * BLKT;
        tile[c] = xqb[c];
    }
    __syncthreads();

    // ---- this wave's query point (uniform -> scalar load) ----
    const int nu = __builtin_amdgcn_readfirstlane(n0 + w);
    const float4 pv = xqb[nu];
    const float q0 = 2.f * pv.x, q1 = 2.f * pv.y, q2 = 2.f * pv.z;

    // ---- phase A: 2048 LDS candidates, keep d[32] in regs ----
    float d[32];
    float vmax = -INFINITY;
    #pragma unroll
    for (int g = 0; g < 4; ++g) {
        float4 cc[8];
        #pragma unroll
        for (int u = 0; u < 8; ++u) cc[u] = tile[(g * 8 + u) * 64 + lane];
        #pragma unroll
        for (int u = 0; u < 8; ++u) {
            const float e = fmaf(q0, cc[u].x, fmaf(q1, cc[u].y, fmaf(q2, cc[u].z, cc[u].w)));
            d[g * 8 + u] = e;
            vmax = fmaxf(vmax, e);
        }
    }

    // ---- threshold: bitonic (desc) of 64 phase-A lane maxima; T = 20th ----
    // The 20 top lane-maxima are 20 distinct candidates >= T, so the global
    // 20th-best >= T; hence {all 4096 candidates >= T} contains the true top-20.
    float T;
    {
        float v = vmax;
        #pragma unroll
        for (int k = 2; k <= 64; k <<= 1) {
            #pragma unroll
            for (int j = k >> 1; j > 0; j >>= 1) {
                const float o = __shfl_xor(v, j, 64);
                const bool keep_min = ((lane & j) == 0) == ((lane & k) != 0);
                v = keep_min ? fminf(v, o) : fmaxf(v, o);
            }
        }
        T = __shfl(v, 19, 64);
    }

    // ---- compact phase-A survivors (ballot-ranked, no atomics) ----
    const int invl = (NPTS - 1) - lane;
    int base = 0;
    #pragma unroll
    for (int j = 0; j < 32; ++j) {
        const bool surv = d[j] >= T;
        const unsigned long long mk = __ballot(surv);
        if (mk) {
            if (surv) {
                const int pos = base + mbcnt64(mk);
                if (pos < PCAP)
                    pool[w * PCAP + pos] =
                        ((unsigned long long)ord32(d[j]) << 32) |
                        (unsigned)(invl - j * 64);       // tie -> lower idx wins
            }
            base += __popcll(mk);
        }
    }

    // ---- phase B: stream 2048 global candidates, filter vs T, no storage ----
    #pragma unroll
    for (int g = 4; g < 8; ++g) {
        float4 cc[8];
        #pragma unroll
        for (int u = 0; u < 8; ++u) cc[u] = xqb[(g * 8 + u) * 64 + lane];
        #pragma unroll
        for (int u = 0; u < 8; ++u) {
            const float e = fmaf(q0, cc[u].x, fmaf(q1, cc[u].y, fmaf(q2, cc[u].z, cc[u].w)));
            const bool surv = e >= T;
            const unsigned long long mk = __ballot(surv);
            if (mk) {
                if (surv) {
                    const int pos = base + mbcnt64(mk);
                    if (pos < PCAP)
                        pool[w * PCAP + pos] =
                            ((unsigned long long)ord32(e) << 32) |
                            (unsigned)(invl - (g * 8 + u) * 64);
                }
                base += __popcll(mk);
            }
        }
    }
    const int cnt = (base < PCAP) ? base : PCAP;         // cnt >= 20 guaranteed

    // ---- exact top-20 set selection (order irrelevant for max-pool) ----
    unsigned long long kk = 0ull;
    if (lane < cnt) kk = pool[w * PCAP + lane];

    if (cnt <= 64) {
        const unsigned key = (unsigned)(kk >> 32);
        unsigned v = key;
        #pragma unroll
        for (int k = 2; k <= 64; k <<= 1) {
            #pragma unroll
            for (int j = k >> 1; j > 0; j >>= 1) {
                const unsigned o = (unsigned)__shfl_xor((int)v, j, 64);
                const bool keep_min = ((lane & j) == 0) == ((lane & k) != 0);
                v = keep_min ? min(v, o) : max(v, o);
            }
        }
        const unsigned K20 = (unsigned)__shfl((int)v, 19, 64);
        const unsigned long long ge = __ballot(key >= K20);  // pad key never matches
        if (__popcll(ge) == KNN) {
            if (key >= K20) idxs[w][mbcnt64(ge)] = (unsigned)kk;
        } else {
            // rare tie path: full u64 sort (value desc, index asc)
            unsigned long long key64 = kk;
            #pragma unroll
            for (int k = 2; k <= 64; k <<= 1) {
                #pragma unroll
                for (int j = k >> 1; j > 0; j >>= 1) {
                    const unsigned long long o = __shfl_xor(key64, j, 64);
                    const bool keep_min = ((lane & j) == 0) == ((lane & k) != 0);
                    const unsigned long long mn = (key64 < o) ? key64 : o;
                    const unsigned long long mx = (key64 < o) ? o : key64;
                    key64 = keep_min ? mn : mx;
                }
            }
            if (lane < KNN) idxs[w][lane] = (unsigned)key64;
        }
    } else {
        // overflow path (~10%): 20 extraction rounds over the pool.
        // Winners go to idxs (disjoint from pool) — no aliasing with live scans.
        for (int r = 0; r < KNN; ++r) {
            unsigned long long bk = 0ull; int bp = -1;
            for (int i = lane; i < cnt; i += 64) {
                const unsigned long long e = pool[w * PCAP + i];
                if (e > bk) { bk = e; bp = i; }
            }
            unsigned long long rb = bk;
            #pragma unroll
            for (int s = 32; s > 0; s >>= 1) {
                const unsigned long long o = __shfl_xor(rb, s, 64);
                if (o > rb) rb = o;
            }
            if (bk == rb && bp >= 0) pool[w * PCAP + bp] = 0ull;  // unique keys
            if (lane == 0) idxs[w][r] = (unsigned)rb;
        }
    }

    // pull the 20 inverted indices into a register
    const unsigned myidx = idxs[w][(lane < KNN) ? lane : 0];

    __syncthreads();   // all waves done with pools -> safe to reuse as outT

    // ---- epilogue: lane = output channel; neighbors via scalar loads ----
    const int o = lane;
    const float iv   = gamma[o] / sqrtf(var[o] + 1e-5f);
    const float bias = beta[o] - mean[o] * iv;
    const float* Wr = Wm + o * 6;
    const float w0p = Wr[0] * iv, w1p = Wr[1] * iv, w2p = Wr[2] * iv;
    const float w3p = Wr[3] * iv, w4p = Wr[4] * iv, w5p = Wr[5] * iv;
    const float basep = fmaf(w3p, pv.x, fmaf(w4p, pv.y, fmaf(w5p, pv.z, bias)));

    float best = -INFINITY;
    #pragma unroll
    for (int k = 0; k < KNN; ++k) {
        const int lk = __builtin_amdgcn_readlane((int)myidx, k);
        const int gi = __builtin_amdgcn_readfirstlane((NPTS - 1) - lk);
        const float4 f = xqb[gi];                        // uniform -> s_load_dwordx4
        float y = fmaf(w0p, f.x - pv.x,
                   fmaf(w1p, f.y - pv.y,
                    fmaf(w2p, f.z - pv.z, basep)));
        y = fmaxf(y, 0.2f * y);                          // LeakyReLU
        best = fmaxf(best, y);
    }

    float* outT = (float*)pool;                          // 64 x 9 padded
    outT[o * 9 + w] = best;
    __syncthreads();

    // ---- output: 2 x float4 per channel row ----
    if (t < NOUT * 2) {
        const int oo = t >> 1, seg = t & 1;
        const int sb = oo * 9 + seg * 4;
        float4 vv;
        vv.x = outT[sb + 0]; vv.y = outT[sb + 1];
        vv.z = outT[sb + 2]; vv.w = outT[sb + 3];
        *(float4*)(out + ((size_t)b * NOUT + oo) * NPTS + n0 + seg * 4) = vv;
    }
}

extern "C" void kernel_launch(void* const* d_in, const int* in_sizes, int n_in,
                              void* d_out, int out_size, void* d_ws, size_t ws_size,
                              hipStream_t stream) {
    const float* x     = (const float*)d_in[0];
    const float* Wm    = (const float*)d_in[1];
    const float* gamma = (const float*)d_in[2];
    const float* beta  = (const float*)d_in[3];
    const float* mean  = (const float*)d_in[4];
    const float* var   = (const float*)d_in[5];
    float* out = (float*)d_out;
    float4* xq = (float4*)d_ws;                    // B*NPTS float4 = 512 KB

    const int B = in_sizes[0] / (3 * NPTS);        // 8
    pack_kernel<<<B * NPTS / 256, 256, 0, stream>>>(x, xq);
    const int nblocks = B * (NPTS / QPB);          // 8 * 512 = 4096
    edgeconv_kernel<<<nblocks, BLKT, 0, stream>>>(xq, Wm, gamma, beta, mean, var, out);
}